// Round 6
// baseline (257.482 us; speedup 1.0000x reference)
//
#include <hip/hip_runtime.h>
#include <stdint.h>

// Two-pass select-by-threshold pipeline (R6: occupancy fix — KTILE=64 single
// buffer 16KB LDS, PPART=64 -> 1024 blocks = 4 blocks/CU = 4 waves/SIMD):
//   k_norm_keys : exact fp32 normalize keys -> bf16 kn + invk; zero cnt
//   k_pass1     : bf16 MFMA sims; per-stream running MAX (1 v_max per result)
//   k_thresh    : T = 8th-largest of PPART*16 stream maxima - margin (T<=v8)
//   k_pass2     : recompute bit-identical sims; collect keys >= T (rare atomics)
//   k_final     : exact fp32 re-dot of <=32 candidates -> top-8, softmax, gather
// ws: [kn N*256B][invk N*4][smax Q*PPART*16*4][thr Q*4][cnt Q*4][cbuf Q*32*4]

typedef unsigned int u32;
typedef unsigned long long u64;
typedef unsigned short u16;
typedef __attribute__((ext_vector_type(4))) float f32x4;
typedef __attribute__((ext_vector_type(2))) float f32x2;
typedef __attribute__((ext_vector_type(4))) int i32x4;
typedef __attribute__((ext_vector_type(8))) short s16x8;  // 8 bf16 in 4 VGPRs

#define D 128
#define KTILE 64     // keys per LDS tile (16 KB, single buffer)
#define QW 64        // queries per wave
#define QB 256       // queries per block (4 waves)
#define CMAX 32      // candidate buffer per query
#define MARGIN 0.05f // threshold safety margin (cheap: a few extra candidates)
#define TBYTES (KTILE * 256)

__device__ __forceinline__ u16 f2bf(float f) {           // RNE float->bf16
    u32 b = __float_as_uint(f);
    b += 0x7FFFu + ((b >> 16) & 1u);
    return (u16)(b >> 16);
}
__device__ __forceinline__ u32 ford(float f) {            // order-preserving f32->u32
    u32 b = __float_as_uint(f);
    return (b & 0x80000000u) ? ~b : (b | 0x80000000u);
}
__device__ __forceinline__ float ford_inv(u32 ob) {
    u32 b = (ob & 0x80000000u) ? (ob ^ 0x80000000u) : ~ob;
    return __uint_as_float(b);
}

// ---------------- kernel 1: normalize keys -> bf16, invk; zero cnt ----------
__global__ __launch_bounds__(256) void k_norm_keys(
        const float* __restrict__ keys, u16* __restrict__ kn,
        float* __restrict__ invk, u32* __restrict__ cnt, int N, int Q) {
    int row = blockIdx.x * 4 + (threadIdx.x >> 6);
    int lane = threadIdx.x & 63;
    if (row >= N) return;
    if (row < Q && lane == 0) cnt[row] = 0u;
    const float* kr = keys + (size_t)row * D;
    f32x2 v = *(const f32x2*)(kr + lane * 2);
    float ss = v.x * v.x + v.y * v.y;
    #pragma unroll
    for (int o = 1; o < 64; o <<= 1) ss += __shfl_xor(ss, o);
    float inv = 1.0f / fmaxf(sqrtf(ss), 1e-12f);
    if (lane == 0) invk[row] = inv;
    u32 packed = (u32)f2bf(v.x * inv) | ((u32)f2bf(v.y * inv) << 16);
    *(u32*)(kn + (size_t)row * D + lane * 2) = packed;
}

// A fragments: raw q rows -> bf16 (selection is invariant to the positive
// 1/|q| scale; exact scale applied in k_final).
__device__ __forceinline__ void load_afr(const float* q, int qrow_base,
                                         int lrow, int lhi, s16x8 afr[4]) {
    const float* qrow = q + (size_t)(qrow_base + lrow) * D + lhi * 8;
    #pragma unroll
    for (int s = 0; s < 4; ++s) {
        f32x4 a = *(const f32x4*)(qrow + s * 32);
        f32x4 b = *(const f32x4*)(qrow + s * 32 + 4);
        union { s16x8 v; u16 e[8]; } cv;
        cv.e[0]=f2bf(a.x); cv.e[1]=f2bf(a.y); cv.e[2]=f2bf(a.z); cv.e[3]=f2bf(a.w);
        cv.e[4]=f2bf(b.x); cv.e[5]=f2bf(b.y); cv.e[6]=f2bf(b.z); cv.e[7]=f2bf(b.w);
        afr[s] = cv.v;
    }
}

// Block id -> (p, qb): group the nqb query-blocks of one key partition on one
// XCD (consecutive bids round-robin XCDs). Bijective when PPART % 8 == 0.
__device__ __forceinline__ void decode_bid(int bid, int nqb, int PPART,
                                           int& p, int& qb) {
    if ((PPART & 7) == 0) {
        int xcd = bid & 7, seq = bid >> 3;
        qb = seq % nqb;
        p  = (seq / nqb) * 8 + xcd;
    } else {
        p = bid / nqb; qb = bid % nqb;
    }
}

// LDS swizzle contract: slot (row r, 16B-granule g) holds global granule
// g ^ (r&15).  Writes: register-staged ds_write_b128 at granule (g^(r&15)).
// Reads: slot granule (4s+lhi)^lrow at row kt*16+lrow -> global chunk 4s+lhi.

// ---------------- kernel 2: pass 1 — per-stream max ------------------------
__global__ __launch_bounds__(256, 4) void k_pass1(
        const u16* __restrict__ kn, const float* __restrict__ q,
        float* __restrict__ smax, int Q, int N, int PPART) {
    __shared__ __align__(16) char lds[TBYTES];   // 16 KB single buffer
    const int tid = threadIdx.x;
    const int wave = tid >> 6, lane = tid & 63;
    const int lrow = lane & 15, lhi = lane >> 4;
    const int nqb = Q / QB;
    int p, qb;
    decode_bid(blockIdx.x, nqb, PPART, p, qb);
    const int part = N / PPART;
    const int key0 = p * part;
    const int qbase = qb * QB + wave * QW;

    s16x8 afr[4][4];
    #pragma unroll
    for (int qs = 0; qs < 4; ++qs) load_afr(q, qbase + qs * 16, lrow, lhi, afr[qs]);

    float m[4][4];   // [qs][r] stream max, folded over kb & kt
    #pragma unroll
    for (int qs = 0; qs < 4; ++qs)
        #pragma unroll
        for (int r = 0; r < 4; ++r) m[qs][r] = -3.0e38f;

    int roff[4];
    #pragma unroll
    for (int s = 0; s < 4; ++s)
        roff[s] = lrow * 256 + ((((s << 2) + lhi) ^ lrow) << 4);

    // staging: thread t -> row t>>2, granules (t&3)*4 + 0..3 (64B contiguous)
    const int srow = tid >> 2;
    const int sg0  = (tid & 3) << 2;
    const int sx   = srow & 15;
    int woff[4];
    #pragma unroll
    for (int i = 0; i < 4; ++i) woff[i] = srow * 256 + (((sg0 + i) ^ sx) << 4);
    const char* gsrc = (const char*)kn + ((size_t)(key0 + srow)) * 256 + sg0 * 16;

    const int iters = part / KTILE;
    i32x4 v[4];
    #pragma unroll
    for (int i = 0; i < 4; ++i) v[i] = *(const i32x4*)(gsrc + i * 16);

    for (int kb = 0; kb < iters; ++kb) {
        __syncthreads();   // (A) prev-tile readers done (drains long-landed loads)
        #pragma unroll
        for (int i = 0; i < 4; ++i) *(i32x4*)(lds + woff[i]) = v[i];
        __syncthreads();   // (B) writes visible
        if (kb + 1 < iters) {   // issue AFTER barrier: drained only at next (A)
            const char* gn = gsrc + (size_t)(kb + 1) * TBYTES;
            #pragma unroll
            for (int i = 0; i < 4; ++i) v[i] = *(const i32x4*)(gn + i * 16);
        }
        __builtin_amdgcn_s_setprio(1);
        #pragma unroll
        for (int kt = 0; kt < 4; ++kt) {
            s16x8 bfr[4];
            #pragma unroll
            for (int s = 0; s < 4; ++s)
                bfr[s] = *(const s16x8*)(lds + roff[s] + kt * 4096);
            #pragma unroll
            for (int qs = 0; qs < 4; ++qs) {
                f32x4 acc = {0.f, 0.f, 0.f, 0.f};
                #pragma unroll
                for (int s = 0; s < 4; ++s)
                    acc = __builtin_amdgcn_mfma_f32_16x16x32_bf16(afr[qs][s], bfr[s], acc, 0, 0, 0);
                #pragma unroll
                for (int r = 0; r < 4; ++r)
                    m[qs][r] = fmaxf(m[qs][r], acc[r]);
            }
        }
        __builtin_amdgcn_s_setprio(0);
    }
    const int stride = PPART * 16;
    #pragma unroll
    for (int qs = 0; qs < 4; ++qs)
        #pragma unroll
        for (int r = 0; r < 4; ++r) {
            int qq = qbase + qs * 16 + (lhi << 2) + r;
            smax[(size_t)qq * stride + p * 16 + lrow] = m[qs][r];
        }
}

// ---------------- kernel 3: per-query threshold -----------------------------
__global__ __launch_bounds__(256) void k_thresh(
        const float* __restrict__ smax, float* __restrict__ thr, int PP) {
    const int wave = threadIdx.x >> 6, lane = threadIdx.x & 63;
    const int qq = blockIdx.x * 4 + wave;
    const int S = PP * 16;           // streams per query
    const int nv = S >> 6;           // regs per lane (<= 16)
    const float* sq = smax + (size_t)qq * S;
    float v[16];
    #pragma unroll
    for (int i = 0; i < 16; ++i) v[i] = (i < nv) ? sq[i * 64 + lane] : -3.0e38f;
    float h = -3.0e38f;
    #pragma unroll
    for (int round = 0; round < 8; ++round) {
        h = v[0];
        #pragma unroll
        for (int i = 1; i < 16; ++i) h = fmaxf(h, v[i]);
        #pragma unroll
        for (int o = 1; o < 64; o <<= 1) h = fmaxf(h, __shfl_xor(h, o));
        #pragma unroll
        for (int i = 0; i < 16; ++i) if (v[i] == h) v[i] = -3.0e38f;  // knockout
    }
    if (lane == 0) thr[qq] = h - MARGIN;
}

// ---------------- kernel 4: pass 2 — threshold collect ----------------------
__global__ __launch_bounds__(256, 4) void k_pass2(
        const u16* __restrict__ kn, const float* __restrict__ q,
        const float* __restrict__ thr, u32* __restrict__ cnt,
        u32* __restrict__ cbuf, int Q, int N, int PPART) {
    __shared__ __align__(16) char lds[TBYTES];
    const int tid = threadIdx.x;
    const int wave = tid >> 6, lane = tid & 63;
    const int lrow = lane & 15, lhi = lane >> 4;
    const int nqb = Q / QB;
    int p, qb;
    decode_bid(blockIdx.x, nqb, PPART, p, qb);
    const int part = N / PPART;
    const int key0 = p * part;
    const int qbase = qb * QB + wave * QW;

    s16x8 afr[4][4];
    #pragma unroll
    for (int qs = 0; qs < 4; ++qs) load_afr(q, qbase + qs * 16, lrow, lhi, afr[qs]);

    f32x4 t[4];
    #pragma unroll
    for (int qs = 0; qs < 4; ++qs)
        t[qs] = *(const f32x4*)(thr + qbase + qs * 16 + (lhi << 2));

    int roff[4];
    #pragma unroll
    for (int s = 0; s < 4; ++s)
        roff[s] = lrow * 256 + ((((s << 2) + lhi) ^ lrow) << 4);

    const int srow = tid >> 2;
    const int sg0  = (tid & 3) << 2;
    const int sx   = srow & 15;
    int woff[4];
    #pragma unroll
    for (int i = 0; i < 4; ++i) woff[i] = srow * 256 + (((sg0 + i) ^ sx) << 4);
    const char* gsrc = (const char*)kn + ((size_t)(key0 + srow)) * 256 + sg0 * 16;

    const int iters = part / KTILE;
    i32x4 v[4];
    #pragma unroll
    for (int i = 0; i < 4; ++i) v[i] = *(const i32x4*)(gsrc + i * 16);

    for (int kb = 0; kb < iters; ++kb) {
        __syncthreads();
        #pragma unroll
        for (int i = 0; i < 4; ++i) *(i32x4*)(lds + woff[i]) = v[i];
        __syncthreads();
        if (kb + 1 < iters) {
            const char* gn = gsrc + (size_t)(kb + 1) * TBYTES;
            #pragma unroll
            for (int i = 0; i < 4; ++i) v[i] = *(const i32x4*)(gn + i * 16);
        }
        const int keybase = key0 + kb * KTILE;
        __builtin_amdgcn_s_setprio(1);
        #pragma unroll
        for (int kt = 0; kt < 4; ++kt) {
            s16x8 bfr[4];
            #pragma unroll
            for (int s = 0; s < 4; ++s)
                bfr[s] = *(const s16x8*)(lds + roff[s] + kt * 4096);
            #pragma unroll
            for (int qs = 0; qs < 4; ++qs) {
                f32x4 acc = {0.f, 0.f, 0.f, 0.f};
                #pragma unroll
                for (int s = 0; s < 4; ++s)
                    acc = __builtin_amdgcn_mfma_f32_16x16x32_bf16(afr[qs][s], bfr[s], acc, 0, 0, 0);
                if ((acc[0] >= t[qs][0]) | (acc[1] >= t[qs][1]) |
                    (acc[2] >= t[qs][2]) | (acc[3] >= t[qs][3])) {  // rare
                    const u32 key = (u32)(keybase + (kt << 4) + lrow);
                    #pragma unroll
                    for (int r = 0; r < 4; ++r) {
                        if (acc[r] >= t[qs][r]) {
                            int qq = qbase + qs * 16 + (lhi << 2) + r;
                            u32 pos = atomicAdd(&cnt[qq], 1u);
                            if (pos < CMAX) cbuf[(size_t)qq * CMAX + pos] = key;
                        }
                    }
                }
            }
        }
        __builtin_amdgcn_s_setprio(0);
    }
}

// ---------------- kernel 5: exact refine -> top-8 -> output -----------------
__global__ __launch_bounds__(256) void k_final(
        const float* __restrict__ q, const float* __restrict__ keys,
        const float* __restrict__ vals, const float* __restrict__ invk,
        const u32* __restrict__ cnt, const u32* __restrict__ cbuf,
        float* __restrict__ pred, float* __restrict__ conf, int Q) {
    const int w = threadIdx.x >> 6;
    const int qq = blockIdx.x * 4 + w;
    const int lane = threadIdx.x & 63;
    __shared__ float qs[4][D];

    const float* qrow = q + (size_t)qq * D;
    f32x2 qv = *(const f32x2*)(qrow + lane * 2);
    qs[w][lane * 2] = qv.x; qs[w][lane * 2 + 1] = qv.y;
    float ss = qv.x * qv.x + qv.y * qv.y;
    #pragma unroll
    for (int o = 1; o < 64; o <<= 1) ss += __shfl_xor(ss, o);
    const float invq = 1.0f / fmaxf(sqrtf(ss), 1e-12f);
    __syncthreads();

    const u32 n = min(cnt[qq], (u32)CMAX);   // >= 8 by construction
    const int c = lane >> 1;                 // candidate id (2 lanes each)
    const int half = lane & 1;
    const bool valid = (u32)c < n;
    const u32 key = valid ? cbuf[(size_t)qq * CMAX + c] : 0u;

    const float* kr = keys + (size_t)key * D + half * 64;
    const float* qsp = &qs[w][half * 64];
    float dot = 0.f;
    #pragma unroll
    for (int j = 0; j < 64; j += 4) {
        f32x4 kv = *(const f32x4*)(kr + j);
        dot += kv.x * qsp[j] + kv.y * qsp[j + 1] + kv.z * qsp[j + 2] + kv.w * qsp[j + 3];
    }
    dot += __shfl_xor(dot, 1);
    const float ex = dot * invk[key] * invq;
    u64 pk = valid ? (((u64)ford(ex) << 32) | (u32)(~key)) : 0ull;

    float accA = 0.f, accB = 0.f, wsum = 0.f, vsum = 0.f, vmax = 0.f;
    #pragma unroll
    for (int r = 0; r < 8; ++r) {
        u64 h = pk;
        #pragma unroll
        for (int o = 1; o < 64; o <<= 1) {
            u64 tt = __shfl_xor(h, o);
            h = tt > h ? tt : h;
        }
        const bool ok = (h != 0ull);
        const float v = ford_inv((u32)(h >> 32));
        const u32 idx = ok ? ~((u32)h) : 0u;
        if (r == 0) vmax = v;
        const float wgt = ok ? expf(v - vmax) : 0.f;
        wsum += wgt; vsum += ok ? v : 0.f;
        const float* vr = vals + (size_t)idx * D;
        accA += wgt * vr[lane];
        accB += wgt * vr[lane + 64];
        if (pk == h) pk = 0ull;   // pop winner
    }
    const float inv_ws = 1.0f / wsum;
    pred[(size_t)qq * D + lane] = accA * inv_ws;
    pred[(size_t)qq * D + lane + 64] = accB * inv_ws;
    if (lane == 0) conf[qq] = fminf(fmaxf(vsum * 0.125f, 0.f), 1.f);
}

// ---------------------------------------------------------------------------
extern "C" void kernel_launch(void* const* d_in, const int* in_sizes, int n_in,
                              void* d_out, int out_size, void* d_ws, size_t ws_size,
                              hipStream_t stream) {
    const float* q    = (const float*)d_in[0];
    const float* keys = (const float*)d_in[1];
    const float* vals = (const float*)d_in[2];
    const int Q = in_sizes[0] / D;
    const int N = in_sizes[1] / D;

    int PPART = 64;  // 1024 blocks = 4 blocks/CU; shrink if ws is tight
    auto need = [&](int P) {
        return (size_t)N * D * 2 + (size_t)N * 4 + (size_t)Q * P * 16 * 4 +
               (size_t)Q * 4 * 2 + (size_t)Q * CMAX * 4;
    };
    while (PPART > 2 && need(PPART) > ws_size) PPART >>= 1;

    char* ws = (char*)d_ws;
    size_t off = 0;
    u16*   kn   = (u16*)(ws + off);   off += (size_t)N * D * 2;
    float* invk = (float*)(ws + off); off += (size_t)N * 4;
    float* smax = (float*)(ws + off); off += (size_t)Q * PPART * 16 * 4;
    float* thr  = (float*)(ws + off); off += (size_t)Q * 4;
    u32*   cnt  = (u32*)(ws + off);   off += (size_t)Q * 4;
    u32*   cbuf = (u32*)(ws + off);   off += (size_t)Q * CMAX * 4;

    float* pred = (float*)d_out;
    float* conf = pred + (size_t)Q * D;

    k_norm_keys<<<(N + 3) / 4, 256, 0, stream>>>(keys, kn, invk, cnt, N, Q);
    k_pass1<<<(Q / QB) * PPART, 256, 0, stream>>>(kn, q, smax, Q, N, PPART);
    k_thresh<<<Q / 4, 256, 0, stream>>>(smax, thr, PPART);
    k_pass2<<<(Q / QB) * PPART, 256, 0, stream>>>(kn, q, thr, cnt, cbuf, Q, N, PPART);
    k_final<<<Q / 4, 256, 0, stream>>>(q, keys, vals, invk, cnt, cbuf, pred, conf, Q);
}

// Round 7
// 174.894 us; speedup vs baseline: 1.4722x; 1.4722x over previous
//
#include <hip/hip_runtime.h>
#include <stdint.h>

// Two-pass select-by-threshold pipeline (R7: R6 structure, spill fixed —
// LB(256,2) no-spill regalloc; 16KB LDS tile gives 4 blocks/CU naturally;
// q pre-cast to bf16 (qbf); smax in [p][q][16] coalesced layout):
//   k_norm_keys : normalize keys -> bf16 kn + invk; cast q -> qbf; zero cnt
//   k_pass1     : bf16 MFMA sims; per-stream running MAX (1 v_max per result)
//   k_thresh    : T = 8th-largest of PPART*16 stream maxima - margin (T<=v8)
//   k_pass2     : recompute bit-identical sims; collect keys >= T (rare atomics)
//   k_final     : exact fp32 re-dot of <=32 candidates -> top-8, softmax, gather
// ws: [kn N*256B][invk N*4][qbf Q*256B][smax PPART*Q*16*4][thr Q*4][cnt Q*4][cbuf Q*32*4]

typedef unsigned int u32;
typedef unsigned long long u64;
typedef unsigned short u16;
typedef __attribute__((ext_vector_type(4))) float f32x4;
typedef __attribute__((ext_vector_type(2))) float f32x2;
typedef __attribute__((ext_vector_type(4))) int i32x4;
typedef __attribute__((ext_vector_type(8))) short s16x8;  // 8 bf16 in 4 VGPRs

#define D 128
#define KTILE 64     // keys per LDS tile (16 KB, single buffer)
#define QW 64        // queries per wave
#define QB 256       // queries per block (4 waves)
#define CMAX 32      // candidate buffer per query
#define MARGIN 0.05f // threshold safety margin (cheap: a few extra candidates)
#define TBYTES (KTILE * 256)

__device__ __forceinline__ u16 f2bf(float f) {           // RNE float->bf16
    u32 b = __float_as_uint(f);
    b += 0x7FFFu + ((b >> 16) & 1u);
    return (u16)(b >> 16);
}
__device__ __forceinline__ u32 ford(float f) {            // order-preserving f32->u32
    u32 b = __float_as_uint(f);
    return (b & 0x80000000u) ? ~b : (b | 0x80000000u);
}
__device__ __forceinline__ float ford_inv(u32 ob) {
    u32 b = (ob & 0x80000000u) ? (ob ^ 0x80000000u) : ~ob;
    return __uint_as_float(b);
}

// ------- kernel 1: normalize keys -> bf16 + invk; raw-cast q -> qbf ---------
__global__ __launch_bounds__(256) void k_norm_keys(
        const float* __restrict__ keys, const float* __restrict__ q,
        u16* __restrict__ kn, float* __restrict__ invk, u16* __restrict__ qbf,
        u32* __restrict__ cnt, int N, int Q) {
    int row = blockIdx.x * 4 + (threadIdx.x >> 6);
    int lane = threadIdx.x & 63;
    if (row >= N) return;
    if (row < Q) {
        if (lane == 0) cnt[row] = 0u;
        f32x2 qv = *(const f32x2*)(q + (size_t)row * D + lane * 2);
        u32 qp = (u32)f2bf(qv.x) | ((u32)f2bf(qv.y) << 16);   // RAW cast (scale-free)
        *(u32*)(qbf + (size_t)row * D + lane * 2) = qp;
    }
    const float* kr = keys + (size_t)row * D;
    f32x2 v = *(const f32x2*)(kr + lane * 2);
    float ss = v.x * v.x + v.y * v.y;
    #pragma unroll
    for (int o = 1; o < 64; o <<= 1) ss += __shfl_xor(ss, o);
    float inv = 1.0f / fmaxf(sqrtf(ss), 1e-12f);
    if (lane == 0) invk[row] = inv;
    u32 packed = (u32)f2bf(v.x * inv) | ((u32)f2bf(v.y * inv) << 16);
    *(u32*)(kn + (size_t)row * D + lane * 2) = packed;
}

// A fragments straight from qbf (both passes read identical bits).
__device__ __forceinline__ void load_afr_bf(const u16* qbf, int qrow_base,
                                            int lrow, int lhi, s16x8 afr[4]) {
    const u16* qrow = qbf + (size_t)(qrow_base + lrow) * D + lhi * 8;
    #pragma unroll
    for (int s = 0; s < 4; ++s) afr[s] = *(const s16x8*)(qrow + s * 32);
}

// Block id -> (p, qb): group the nqb query-blocks of one key partition on one
// XCD (consecutive bids round-robin XCDs). Bijective when PPART % 8 == 0.
__device__ __forceinline__ void decode_bid(int bid, int nqb, int PPART,
                                           int& p, int& qb) {
    if ((PPART & 7) == 0) {
        int xcd = bid & 7, seq = bid >> 3;
        qb = seq % nqb;
        p  = (seq / nqb) * 8 + xcd;
    } else {
        p = bid / nqb; qb = bid % nqb;
    }
}

// LDS swizzle contract: slot (row r, 16B-granule g) holds global granule
// g ^ (r&15).  Writes: register-staged ds_write_b128 at granule (g^(r&15)).
// Reads: slot granule (4s+lhi)^lrow at row kt*16+lrow -> global chunk 4s+lhi.

// ---------------- kernel 2: pass 1 — per-stream max ------------------------
__global__ __launch_bounds__(256, 2) void k_pass1(
        const u16* __restrict__ kn, const u16* __restrict__ qbf,
        float* __restrict__ smax, int Q, int N, int PPART) {
    __shared__ __align__(16) char lds[TBYTES];   // 16 KB single buffer
    const int tid = threadIdx.x;
    const int wave = tid >> 6, lane = tid & 63;
    const int lrow = lane & 15, lhi = lane >> 4;
    const int nqb = Q / QB;
    int p, qb;
    decode_bid(blockIdx.x, nqb, PPART, p, qb);
    const int part = N / PPART;
    const int key0 = p * part;
    const int qbase = qb * QB + wave * QW;

    s16x8 afr[4][4];
    #pragma unroll
    for (int qs = 0; qs < 4; ++qs) load_afr_bf(qbf, qbase + qs * 16, lrow, lhi, afr[qs]);

    float m[4][4];   // [qs][r] stream max, folded over kb & kt
    #pragma unroll
    for (int qs = 0; qs < 4; ++qs)
        #pragma unroll
        for (int r = 0; r < 4; ++r) m[qs][r] = -3.0e38f;

    int roff[4];
    #pragma unroll
    for (int s = 0; s < 4; ++s)
        roff[s] = lrow * 256 + ((((s << 2) + lhi) ^ lrow) << 4);

    // staging: thread t -> row t>>2, granules (t&3)*4 + 0..3 (64B contiguous)
    const int srow = tid >> 2;
    const int sg0  = (tid & 3) << 2;
    const int sx   = srow & 15;
    int woff[4];
    #pragma unroll
    for (int i = 0; i < 4; ++i) woff[i] = srow * 256 + (((sg0 + i) ^ sx) << 4);
    const char* gsrc = (const char*)kn + ((size_t)(key0 + srow)) * 256 + sg0 * 16;

    const int iters = part / KTILE;
    i32x4 v[4];
    #pragma unroll
    for (int i = 0; i < 4; ++i) v[i] = *(const i32x4*)(gsrc + i * 16);

    for (int kb = 0; kb < iters; ++kb) {
        __syncthreads();   // (A) prev-tile readers done
        #pragma unroll
        for (int i = 0; i < 4; ++i) *(i32x4*)(lds + woff[i]) = v[i];
        __syncthreads();   // (B) writes visible
        if (kb + 1 < iters) {   // issue AFTER barrier: drained only at next (A)
            const char* gn = gsrc + (size_t)(kb + 1) * TBYTES;
            #pragma unroll
            for (int i = 0; i < 4; ++i) v[i] = *(const i32x4*)(gn + i * 16);
        }
        __builtin_amdgcn_s_setprio(1);
        #pragma unroll
        for (int kt = 0; kt < 4; ++kt) {
            s16x8 bfr[4];
            #pragma unroll
            for (int s = 0; s < 4; ++s)
                bfr[s] = *(const s16x8*)(lds + roff[s] + kt * 4096);
            #pragma unroll
            for (int qs = 0; qs < 4; ++qs) {
                f32x4 acc = {0.f, 0.f, 0.f, 0.f};
                #pragma unroll
                for (int s = 0; s < 4; ++s)
                    acc = __builtin_amdgcn_mfma_f32_16x16x32_bf16(afr[qs][s], bfr[s], acc, 0, 0, 0);
                #pragma unroll
                for (int r = 0; r < 4; ++r)
                    m[qs][r] = fmaxf(m[qs][r], acc[r]);
            }
        }
        __builtin_amdgcn_s_setprio(0);
    }
    // smax layout [p][q][16]: block writes one contiguous 16KB run
    #pragma unroll
    for (int qs = 0; qs < 4; ++qs)
        #pragma unroll
        for (int r = 0; r < 4; ++r) {
            int qq = qbase + qs * 16 + (lhi << 2) + r;
            smax[((size_t)p * Q + qq) * 16 + lrow] = m[qs][r];
        }
}

// ---------------- kernel 3: per-query threshold -----------------------------
__global__ __launch_bounds__(256) void k_thresh(
        const float* __restrict__ smax, float* __restrict__ thr, int Q, int PP) {
    const int wave = threadIdx.x >> 6, lane = threadIdx.x & 63;
    const int qq = blockIdx.x * 4 + wave;
    const int lrow = lane & 15, lhi = lane >> 4;
    const int nv = PP >> 2;          // regs per lane (p = i*4 + lhi)
    float v[16];
    #pragma unroll
    for (int i = 0; i < 16; ++i)
        v[i] = (i < nv) ? smax[((size_t)(i * 4 + lhi) * Q + qq) * 16 + lrow]
                        : -3.0e38f;
    float h = -3.0e38f;
    #pragma unroll
    for (int round = 0; round < 8; ++round) {
        h = v[0];
        #pragma unroll
        for (int i = 1; i < 16; ++i) h = fmaxf(h, v[i]);
        #pragma unroll
        for (int o = 1; o < 64; o <<= 1) h = fmaxf(h, __shfl_xor(h, o));
        #pragma unroll
        for (int i = 0; i < 16; ++i) if (v[i] == h) v[i] = -3.0e38f;  // knockout
    }
    if (lane == 0) thr[qq] = h - MARGIN;
}

// ---------------- kernel 4: pass 2 — threshold collect ----------------------
__global__ __launch_bounds__(256, 2) void k_pass2(
        const u16* __restrict__ kn, const u16* __restrict__ qbf,
        const float* __restrict__ thr, u32* __restrict__ cnt,
        u32* __restrict__ cbuf, int Q, int N, int PPART) {
    __shared__ __align__(16) char lds[TBYTES];
    const int tid = threadIdx.x;
    const int wave = tid >> 6, lane = tid & 63;
    const int lrow = lane & 15, lhi = lane >> 4;
    const int nqb = Q / QB;
    int p, qb;
    decode_bid(blockIdx.x, nqb, PPART, p, qb);
    const int part = N / PPART;
    const int key0 = p * part;
    const int qbase = qb * QB + wave * QW;

    s16x8 afr[4][4];
    #pragma unroll
    for (int qs = 0; qs < 4; ++qs) load_afr_bf(qbf, qbase + qs * 16, lrow, lhi, afr[qs]);

    f32x4 t[4];
    #pragma unroll
    for (int qs = 0; qs < 4; ++qs)
        t[qs] = *(const f32x4*)(thr + qbase + qs * 16 + (lhi << 2));

    int roff[4];
    #pragma unroll
    for (int s = 0; s < 4; ++s)
        roff[s] = lrow * 256 + ((((s << 2) + lhi) ^ lrow) << 4);

    const int srow = tid >> 2;
    const int sg0  = (tid & 3) << 2;
    const int sx   = srow & 15;
    int woff[4];
    #pragma unroll
    for (int i = 0; i < 4; ++i) woff[i] = srow * 256 + (((sg0 + i) ^ sx) << 4);
    const char* gsrc = (const char*)kn + ((size_t)(key0 + srow)) * 256 + sg0 * 16;

    const int iters = part / KTILE;
    i32x4 v[4];
    #pragma unroll
    for (int i = 0; i < 4; ++i) v[i] = *(const i32x4*)(gsrc + i * 16);

    for (int kb = 0; kb < iters; ++kb) {
        __syncthreads();
        #pragma unroll
        for (int i = 0; i < 4; ++i) *(i32x4*)(lds + woff[i]) = v[i];
        __syncthreads();
        if (kb + 1 < iters) {
            const char* gn = gsrc + (size_t)(kb + 1) * TBYTES;
            #pragma unroll
            for (int i = 0; i < 4; ++i) v[i] = *(const i32x4*)(gn + i * 16);
        }
        const int keybase = key0 + kb * KTILE;
        __builtin_amdgcn_s_setprio(1);
        #pragma unroll
        for (int kt = 0; kt < 4; ++kt) {
            s16x8 bfr[4];
            #pragma unroll
            for (int s = 0; s < 4; ++s)
                bfr[s] = *(const s16x8*)(lds + roff[s] + kt * 4096);
            #pragma unroll
            for (int qs = 0; qs < 4; ++qs) {
                f32x4 acc = {0.f, 0.f, 0.f, 0.f};
                #pragma unroll
                for (int s = 0; s < 4; ++s)
                    acc = __builtin_amdgcn_mfma_f32_16x16x32_bf16(afr[qs][s], bfr[s], acc, 0, 0, 0);
                if ((acc[0] >= t[qs][0]) | (acc[1] >= t[qs][1]) |
                    (acc[2] >= t[qs][2]) | (acc[3] >= t[qs][3])) {  // rare
                    const u32 key = (u32)(keybase + (kt << 4) + lrow);
                    #pragma unroll
                    for (int r = 0; r < 4; ++r) {
                        if (acc[r] >= t[qs][r]) {
                            int qq = qbase + qs * 16 + (lhi << 2) + r;
                            u32 pos = atomicAdd(&cnt[qq], 1u);
                            if (pos < CMAX) cbuf[(size_t)qq * CMAX + pos] = key;
                        }
                    }
                }
            }
        }
        __builtin_amdgcn_s_setprio(0);
    }
}

// ---------------- kernel 5: exact refine -> top-8 -> output -----------------
__global__ __launch_bounds__(256) void k_final(
        const float* __restrict__ q, const float* __restrict__ keys,
        const float* __restrict__ vals, const float* __restrict__ invk,
        const u32* __restrict__ cnt, const u32* __restrict__ cbuf,
        float* __restrict__ pred, float* __restrict__ conf, int Q) {
    const int w = threadIdx.x >> 6;
    const int qq = blockIdx.x * 4 + w;
    const int lane = threadIdx.x & 63;
    __shared__ float qs[4][D];

    const float* qrow = q + (size_t)qq * D;
    f32x2 qv = *(const f32x2*)(qrow + lane * 2);
    qs[w][lane * 2] = qv.x; qs[w][lane * 2 + 1] = qv.y;
    float ss = qv.x * qv.x + qv.y * qv.y;
    #pragma unroll
    for (int o = 1; o < 64; o <<= 1) ss += __shfl_xor(ss, o);
    const float invq = 1.0f / fmaxf(sqrtf(ss), 1e-12f);
    __syncthreads();

    const u32 n = min(cnt[qq], (u32)CMAX);   // >= 8 by construction
    const int c = lane >> 1;                 // candidate id (2 lanes each)
    const int half = lane & 1;
    const bool valid = (u32)c < n;
    const u32 key = valid ? cbuf[(size_t)qq * CMAX + c] : 0u;

    const float* kr = keys + (size_t)key * D + half * 64;
    const float* qsp = &qs[w][half * 64];
    float dot = 0.f;
    #pragma unroll
    for (int j = 0; j < 64; j += 4) {
        f32x4 kv = *(const f32x4*)(kr + j);
        dot += kv.x * qsp[j] + kv.y * qsp[j + 1] + kv.z * qsp[j + 2] + kv.w * qsp[j + 3];
    }
    dot += __shfl_xor(dot, 1);
    const float ex = dot * invk[key] * invq;
    u64 pk = valid ? (((u64)ford(ex) << 32) | (u32)(~key)) : 0ull;

    float accA = 0.f, accB = 0.f, wsum = 0.f, vsum = 0.f, vmax = 0.f;
    #pragma unroll
    for (int r = 0; r < 8; ++r) {
        u64 h = pk;
        #pragma unroll
        for (int o = 1; o < 64; o <<= 1) {
            u64 tt = __shfl_xor(h, o);
            h = tt > h ? tt : h;
        }
        const bool ok = (h != 0ull);
        const float v = ford_inv((u32)(h >> 32));
        const u32 idx = ok ? ~((u32)h) : 0u;
        if (r == 0) vmax = v;
        const float wgt = ok ? expf(v - vmax) : 0.f;
        wsum += wgt; vsum += ok ? v : 0.f;
        const float* vr = vals + (size_t)idx * D;
        accA += wgt * vr[lane];
        accB += wgt * vr[lane + 64];
        if (pk == h) pk = 0ull;   // pop winner
    }
    const float inv_ws = 1.0f / wsum;
    pred[(size_t)qq * D + lane] = accA * inv_ws;
    pred[(size_t)qq * D + lane + 64] = accB * inv_ws;
    if (lane == 0) conf[qq] = fminf(fmaxf(vsum * 0.125f, 0.f), 1.f);
}

// ---------------------------------------------------------------------------
extern "C" void kernel_launch(void* const* d_in, const int* in_sizes, int n_in,
                              void* d_out, int out_size, void* d_ws, size_t ws_size,
                              hipStream_t stream) {
    const float* q    = (const float*)d_in[0];
    const float* keys = (const float*)d_in[1];
    const float* vals = (const float*)d_in[2];
    const int Q = in_sizes[0] / D;
    const int N = in_sizes[1] / D;

    int PPART = 64;  // 1024 blocks; shrink if ws is tight
    auto need = [&](int P) {
        return (size_t)N * D * 2 + (size_t)N * 4 + (size_t)Q * D * 2 +
               (size_t)Q * P * 16 * 4 + (size_t)Q * 4 * 2 + (size_t)Q * CMAX * 4;
    };
    while (PPART > 2 && need(PPART) > ws_size) PPART >>= 1;

    char* ws = (char*)d_ws;
    size_t off = 0;
    u16*   kn   = (u16*)(ws + off);   off += (size_t)N * D * 2;
    float* invk = (float*)(ws + off); off += (size_t)N * 4;
    u16*   qbf  = (u16*)(ws + off);   off += (size_t)Q * D * 2;
    float* smax = (float*)(ws + off); off += (size_t)Q * PPART * 16 * 4;
    float* thr  = (float*)(ws + off); off += (size_t)Q * 4;
    u32*   cnt  = (u32*)(ws + off);   off += (size_t)Q * 4;
    u32*   cbuf = (u32*)(ws + off);   off += (size_t)Q * CMAX * 4;

    float* pred = (float*)d_out;
    float* conf = pred + (size_t)Q * D;

    k_norm_keys<<<(N + 3) / 4, 256, 0, stream>>>(keys, q, kn, invk, qbf, cnt, N, Q);
    k_pass1<<<(Q / QB) * PPART, 256, 0, stream>>>(kn, qbf, smax, Q, N, PPART);
    k_thresh<<<Q / 4, 256, 0, stream>>>(smax, thr, Q, PPART);
    k_pass2<<<(Q / QB) * PPART, 256, 0, stream>>>(kn, qbf, thr, cnt, cbuf, Q, N, PPART);
    k_final<<<Q / 4, 256, 0, stream>>>(q, keys, vals, invk, cnt, cbuf, pred, conf, Q);
}